// Round 1
// baseline (853.602 us; speedup 1.0000x reference)
//
#include <hip/hip_runtime.h>
#include <hip/hip_fp16.h>

// workspace layout (float offsets)
#define WS_APW   0          // 4*64*256      = 65536   apow[i][v][hn]
#define WS_BSG   65536      // 2*256         = 512     sigmoid(B_s)[hn]
#define WS_OUTS  66048      // 2*1024*256    = 524288  outs[d][l][hn]
#define WS_KC    590336     // 32*63*64      = 129024  Kcomb[c][U][V] (V=63 zero pad)
#define WS_XT    719360     // 8*32*64*64    = 1048576 x transposed [b][c][p][q]
#define WS_YC    1767936    // 8*32*64*64    = 1048576 conv result  [b][c][p][q]

// ---------------- K0: sigmoid powers table ----------------
__global__ void k0_prep(const float* __restrict__ A1, const float* __restrict__ A2,
                        const float* __restrict__ A3, const float* __restrict__ A4,
                        const float* __restrict__ B1, const float* __restrict__ B2,
                        float* __restrict__ apw, float* __restrict__ bsg) {
  const int t = threadIdx.x;  // hn in [0,256)
  const float* As[4] = {A1, A2, A3, A4};
  #pragma unroll
  for (int i = 0; i < 4; ++i) {
    const float a = As[i][t];
    const float s = 1.0f / (1.0f + expf(-a));
    float p = 1.0f;
    for (int v = 0; v < 64; ++v) {
      apw[(i * 64 + v) * 256 + t] = p;   // sigmoid(A_i[hn])^v
      p *= s;
    }
  }
  bsg[t]       = 1.0f / (1.0f + expf(-B1[t]));
  bsg[256 + t] = 1.0f / (1.0f + expf(-B2[t]));
}

// ---------------- K1: SSM kernel contraction ----------------
// outs[d][l][hn] = sum_j  prod_i ( sum_v M_i[l*64+j,v]*apow_i[v,hn] ) * Bdot
// lane = j, wave handles 64 hn (8 chunks of 8). M staged fp16 (2 mats/dword) in LDS.
__global__ __launch_bounds__(256, 4) void k1_stage2(
    const float* __restrict__ Mh0, const float* __restrict__ Mh1,
    const float* __restrict__ Mh2, const float* __restrict__ Mh3,
    const float* __restrict__ MhB,
    const float* __restrict__ Mv0, const float* __restrict__ Mv1,
    const float* __restrict__ Mv2, const float* __restrict__ Mv3,
    const float* __restrict__ MvB,
    const float* __restrict__ apw, const float* __restrict__ bsg,
    float* __restrict__ outs) {
  __shared__ __half2 MT01[64 * 64];  // [v][j] -> (M0,M1)
  __shared__ __half2 MT23[64 * 64];  // [v][j] -> (M2,M3)
  __shared__ float   MBs[128];       // [j][s]

  const int bd = blockIdx.x >> 10;       // 0=h, 1=v
  const int l  = blockIdx.x & 1023;
  const float* M0 = bd ? Mv0 : Mh0;
  const float* M1 = bd ? Mv1 : Mh1;
  const float* M2 = bd ? Mv2 : Mh2;
  const float* M3 = bd ? Mv3 : Mh3;
  const float* MB = bd ? MvB : MhB;

  const int t  = threadIdx.x;
  const int j  = t & 63;
  const int c4 = t >> 6;

  // stage + transpose M rows l*64+j
  #pragma unroll
  for (int cc = 0; cc < 4; ++cc) {
    const int vb = (cc * 4 + c4) * 4;
    const int gb = (l * 64 + j) * 64 + vb;
    const float4 q0 = *(const float4*)(M0 + gb);
    const float4 q1 = *(const float4*)(M1 + gb);
    const float4 q2 = *(const float4*)(M2 + gb);
    const float4 q3 = *(const float4*)(M3 + gb);
    MT01[(vb + 0) * 64 + j] = __floats2half2_rn(q0.x, q1.x);
    MT01[(vb + 1) * 64 + j] = __floats2half2_rn(q0.y, q1.y);
    MT01[(vb + 2) * 64 + j] = __floats2half2_rn(q0.z, q1.z);
    MT01[(vb + 3) * 64 + j] = __floats2half2_rn(q0.w, q1.w);
    MT23[(vb + 0) * 64 + j] = __floats2half2_rn(q2.x, q3.x);
    MT23[(vb + 1) * 64 + j] = __floats2half2_rn(q2.y, q3.y);
    MT23[(vb + 2) * 64 + j] = __floats2half2_rn(q2.z, q3.z);
    MT23[(vb + 3) * 64 + j] = __floats2half2_rn(q2.w, q3.w);
  }
  if (t < 64) {
    MBs[2 * t]     = MB[(l * 64 + t) * 2 + 0];
    MBs[2 * t + 1] = MB[(l * 64 + t) * 2 + 1];
  }
  __syncthreads();

  const int wv = __builtin_amdgcn_readfirstlane(t >> 6);  // wave id, uniform
  const float mb0 = MBs[2 * j], mb1 = MBs[2 * j + 1];

  for (int chunk = 0; chunk < 8; ++chunk) {
    const int hn0 = wv * 64 + chunk * 8;   // uniform -> scalar loads of apw
    float D0[8], D1[8], D2[8], D3[8];
    #pragma unroll
    for (int h = 0; h < 8; ++h) { D0[h] = 0.f; D1[h] = 0.f; D2[h] = 0.f; D3[h] = 0.f; }

    #pragma unroll 4
    for (int v = 0; v < 64; ++v) {
      const float2 f01 = __half22float2(MT01[v * 64 + j]);
      const float2 f23 = __half22float2(MT23[v * 64 + j]);
      const float* a0 = apw + (v * 256 + hn0);
      const float* a1 = apw + (16384 + v * 256 + hn0);
      const float* a2 = apw + (32768 + v * 256 + hn0);
      const float* a3 = apw + (49152 + v * 256 + hn0);
      #pragma unroll
      for (int h = 0; h < 8; ++h) {
        D0[h] = fmaf(f01.x, a0[h], D0[h]);
        D1[h] = fmaf(f01.y, a1[h], D1[h]);
        D2[h] = fmaf(f23.x, a2[h], D2[h]);
        D3[h] = fmaf(f23.y, a3[h], D3[h]);
      }
    }
    const float* b0 = bsg + hn0;
    const float* b1 = bsg + 256 + hn0;
    #pragma unroll
    for (int h = 0; h < 8; ++h) {
      const float db = mb0 * b0[h] + mb1 * b1[h];
      float p = D0[h] * D1[h] * D2[h] * D3[h] * db;
      p += __shfl_xor(p, 1);
      p += __shfl_xor(p, 2);
      p += __shfl_xor(p, 4);
      p += __shfl_xor(p, 8);
      p += __shfl_xor(p, 16);
      p += __shfl_xor(p, 32);
      if (j == h) outs[(bd * 1024 + l) * 256 + hn0 + h] = p;
    }
  }
}

// ---------------- K2: build combined 63x63 kernel ----------------
__global__ void k2_kc(const float* __restrict__ outs, const float* __restrict__ C1,
                      const float* __restrict__ C2, float* __restrict__ kc) {
  const int c = blockIdx.x;  // channel 0..31
  const float SC = 0.70710678118654752f;
  for (int idx = threadIdx.x; idx < 63 * 64; idx += 256) {
    const int U = idx >> 6, V = idx & 63;
    float acc = 0.f;
    if (V < 63) {
      const int u = U - 31, v = V - 31;
      #pragma unroll
      for (int d = 0; d < 4; ++d) {
        const int dy = (d == 1 || d == 3) ? u : -u;
        const int dx = (d == 2 || d == 3) ? v : -v;
        if (dy >= 0 && dy < 32 && dx >= 0 && dx < 32) {
          const int l = dy * 32 + dx;
          const int h = d * 32 + c;
          const float e = (dy == 0 && dx == 0) ? 1.f : ((dy == 0 || dx == 0) ? 2.f : 1.f);
          const float s0 = outs[l * 256 + h * 2 + 0] * C1[h * 2 + 0]
                         + outs[l * 256 + h * 2 + 1] * C1[h * 2 + 1];
          const float s1 = outs[262144 + l * 256 + h * 2 + 0] * C2[h * 2 + 0]
                         + outs[262144 + l * 256 + h * 2 + 1] * C2[h * 2 + 1];
          acc += e * SC * (s0 + s1);
        }
      }
    }
    kc[(c * 63 + U) * 64 + V] = acc;
  }
}

// ---------------- K3: transpose x (b,p,q,c) -> (b,c,p,q) ----------------
__global__ void k3_xt(const float* __restrict__ x, float* __restrict__ xt) {
  __shared__ float ls[8 * 64 * 33];
  const int b = blockIdx.x >> 3, pt = blockIdx.x & 7;
  const int t = threadIdx.x;
  const float* src = x + (b * 8 + pt) * 16384;
  #pragma unroll 8
  for (int k = 0; k < 64; ++k) {
    const int e = t + k * 256;
    const int p = e >> 11, q = (e >> 5) & 63, cl = e & 31;
    ls[(p * 64 + q) * 33 + cl] = src[e];
  }
  __syncthreads();
  #pragma unroll 8
  for (int k = 0; k < 64; ++k) {
    const int o = t + k * 256;
    const int cl = o >> 9, p = (o >> 6) & 7, q = o & 63;
    xt[(b * 32 + cl) * 4096 + (pt * 8 + p) * 64 + q] = ls[(p * 64 + q) * 33 + cl];
  }
}

// ---------------- K4: direct conv with combined kernel ----------------
__global__ __launch_bounds__(256, 2) void k4_conv(const float* __restrict__ xt,
                                                  const float* __restrict__ kc,
                                                  float* __restrict__ y) {
  __shared__ float xp[94 * 128];  // rows p0-31..p0+62, cols -31..95 (zero padded)
  const int blk = blockIdx.x;
  const int bc = blk >> 1;           // b*32+c
  const int p0 = (blk & 1) * 32;
  const int t = threadIdx.x;
  const float* xim = xt + bc * 4096;

  for (int idx = t; idx < 94 * 128; idx += 256) {
    const int r = idx >> 7, ccol = idx & 127;
    const int gp = p0 + r - 31, gq = ccol - 31;
    float vv = 0.f;
    if (gp >= 0 && gp < 64 && gq >= 0 && gq < 64) vv = xim[gp * 64 + gq];
    xp[idx] = vv;
  }
  __syncthreads();

  const int c  = bc & 31;
  const int pl = t >> 3;             // output row (local)
  const int ql = (t & 7) * 8;        // output col base (1x8 tile)
  const float* kcc = kc + c * 63 * 64;

  const int wv  = __builtin_amdgcn_readfirstlane(t >> 6);
  const int plw = wv * 8;            // wave's min pl
  const int Ustart = max(0, 24 - p0 - plw);
  const int Uend   = min(62, 94 - p0 - plw);

  float acc[8];
  #pragma unroll
  for (int q = 0; q < 8; ++q) acc[q] = 0.f;

  for (int U = Ustart; U <= Uend; ++U) {
    const float* xr = xp + (pl + U) * 128 + ql;
    const float* kr = kcc + U * 64;   // uniform -> scalar loads
    #pragma unroll
    for (int Vc = 0; Vc < 64; Vc += 16) {
      float xw[24];
      #pragma unroll
      for (int m = 0; m < 6; ++m) {
        const float4 f4 = *(const float4*)(xr + Vc + m * 4);
        xw[m * 4 + 0] = f4.x; xw[m * 4 + 1] = f4.y;
        xw[m * 4 + 2] = f4.z; xw[m * 4 + 3] = f4.w;
      }
      #pragma unroll
      for (int vv = 0; vv < 16; ++vv) {
        const float kv = kr[Vc + vv];
        #pragma unroll
        for (int q = 0; q < 8; ++q)
          acc[q] = fmaf(kv, xw[vv + q], acc[q]);
      }
    }
  }
  float* yrow = y + bc * 4096 + (p0 + pl) * 64 + ql;
  float4 s0 = {acc[0], acc[1], acc[2], acc[3]};
  float4 s1 = {acc[4], acc[5], acc[6], acc[7]};
  *(float4*)(yrow)     = s0;
  *(float4*)(yrow + 4) = s1;
}

// ---------------- K5: channel mix y @ W^T + b ----------------
__global__ void k5_out(const float* __restrict__ yc, const float* __restrict__ W,
                       const float* __restrict__ bias, float* __restrict__ out) {
  __shared__ float ysh[64 * 33];  // [q][c] padded
  const int b = blockIdx.x >> 6, p = blockIdx.x & 63;
  const int t = threadIdx.x;
  const float* ybp = yc + b * 131072 + p * 64;
  #pragma unroll
  for (int k = 0; k < 8; ++k) {
    const int f = t + k * 256;
    const int cch = f >> 6, q = f & 63;
    ysh[q * 33 + cch] = ybp[cch * 4096 + q];
  }
  const int e = t & 31;
  float wr[32];
  #pragma unroll
  for (int c4 = 0; c4 < 8; ++c4) {
    const float4 f4 = *(const float4*)(W + e * 32 + c4 * 4);
    wr[c4 * 4 + 0] = f4.x; wr[c4 * 4 + 1] = f4.y;
    wr[c4 * 4 + 2] = f4.z; wr[c4 * 4 + 3] = f4.w;
  }
  const float bb = bias[e];
  __syncthreads();
  const int q0 = t >> 5;  // 0..7
  #pragma unroll
  for (int k = 0; k < 8; ++k) {
    const int q = q0 + k * 8;
    float a = bb;
    #pragma unroll
    for (int cc = 0; cc < 32; ++cc) a = fmaf(ysh[q * 33 + cc], wr[cc], a);
    out[((b * 64 + p) * 64 + q) * 32 + e] = a;
  }
}

extern "C" void kernel_launch(void* const* d_in, const int* in_sizes, int n_in,
                              void* d_out, int out_size, void* d_ws, size_t ws_size,
                              hipStream_t stream) {
  const float* x   = (const float*)d_in[0];
  const float* Mh[5] = {(const float*)d_in[1], (const float*)d_in[2], (const float*)d_in[3],
                        (const float*)d_in[4], (const float*)d_in[5]};
  const float* Mv[5] = {(const float*)d_in[6], (const float*)d_in[7], (const float*)d_in[8],
                        (const float*)d_in[9], (const float*)d_in[10]};
  const float* A1 = (const float*)d_in[11];
  const float* A2 = (const float*)d_in[12];
  const float* A3 = (const float*)d_in[13];
  const float* A4 = (const float*)d_in[14];
  const float* B1 = (const float*)d_in[15];
  const float* B2 = (const float*)d_in[16];
  const float* C1 = (const float*)d_in[17];
  const float* C2 = (const float*)d_in[18];
  const float* W  = (const float*)d_in[19];
  const float* bb = (const float*)d_in[20];
  float* ws  = (float*)d_ws;
  float* apw  = ws + WS_APW;
  float* bsg  = ws + WS_BSG;
  float* outs = ws + WS_OUTS;
  float* kc   = ws + WS_KC;
  float* xt   = ws + WS_XT;
  float* yc   = ws + WS_YC;

  k0_prep<<<1, 256, 0, stream>>>(A1, A2, A3, A4, B1, B2, apw, bsg);
  k3_xt<<<64, 256, 0, stream>>>(x, xt);
  k1_stage2<<<2048, 256, 0, stream>>>(Mh[0], Mh[1], Mh[2], Mh[3], Mh[4],
                                      Mv[0], Mv[1], Mv[2], Mv[3], Mv[4],
                                      apw, bsg, outs);
  k2_kc<<<32, 256, 0, stream>>>(outs, C1, C2, kc);
  k4_conv<<<512, 256, 0, stream>>>(xt, kc, yc);
  k5_out<<<512, 256, 0, stream>>>(yc, W, bb, (float*)d_out);
}

// Round 2
// 489.298 us; speedup vs baseline: 1.7445x; 1.7445x over previous
//
#include <hip/hip_runtime.h>
#include <hip/hip_fp16.h>

typedef _Float16 f16x8 __attribute__((ext_vector_type(8)));
typedef _Float16 half4v __attribute__((ext_vector_type(4)));
typedef float float4v __attribute__((ext_vector_type(4)));

// workspace layout (float offsets)
#define WS_BFH   0          // 65536 halfs (32768 floats): apw in MFMA B-frag fp16 layout
#define WS_BSG   65536      // 2*256         = 512     sigmoid(B_s)[hn]
#define WS_OUTS  66048      // 2*1024*256    = 524288  outs[d][l][hn]
#define WS_KC    590336     // 32*63*64      = 129024  Kcomb[c][U][V] (V=63 zero pad)
#define WS_XT    719360     // 8*32*64*64    = 1048576 x transposed [b][c][p][q]
#define WS_YC    1767936    // 8*32*64*64    = 1048576 conv result  [b][c][p][q]

// ---------------- K0: sigmoid powers -> fp16 B-fragment layout ----------------
// Bfh[i][kb][ntile][lane][j] (halfs), value = sigmoid(A_i[hn])^v with
//   hn = ntile*16 + (lane&15),  v = kb*32 + (lane>>4)*8 + j
__global__ void k0_prep(const float* __restrict__ A1, const float* __restrict__ A2,
                        const float* __restrict__ A3, const float* __restrict__ A4,
                        const float* __restrict__ B1, const float* __restrict__ B2,
                        _Float16* __restrict__ Bfh, float* __restrict__ bsg) {
  const int blk = blockIdx.x;        // 0..7 = i*2 + kb
  const int i = blk >> 1, kb = blk & 1;
  const int hn = threadIdx.x;        // 0..255
  const float* As[4] = {A1, A2, A3, A4};
  const float a = As[i][hn];
  const float s = 1.0f / (1.0f + expf(-a));
  float p = 1.0f;
  for (int v = 0; v < kb * 32; ++v) p *= s;
  const int ntile = hn >> 4;
  #pragma unroll
  for (int g = 0; g < 4; ++g) {      // g = lane>>4 group, covers v = kb*32+g*8 .. +8
    _Float16 h[8];
    #pragma unroll
    for (int j = 0; j < 8; ++j) { h[j] = (_Float16)p; p *= s; }
    const int lane = (hn & 15) | (g << 4);
    _Float16* dst = Bfh + ((((i * 2 + kb) * 16 + ntile) * 64 + lane) << 3);
    *(f16x8*)dst = *(f16x8*)h;
  }
  if (blk == 0) {
    bsg[hn]       = 1.0f / (1.0f + expf(-B1[hn]));
    bsg[256 + hn] = 1.0f / (1.0f + expf(-B2[hn]));
  }
}

// ---------------- K1: SSM kernel contraction via MFMA ----------------
// outs[d][l][hn] = sum_j  prod_i ( sum_v M_i[l*64+j,v]*apw_i[v,hn] ) * Bdot[l*64+j,hn]
// Block = (d,l): stage A (4 mats x 64x64 fp32 -> fp16 frag layout) in LDS;
// wave w handles hn quarter w*64..w*64+63 (4 n-tiles of 16).
__global__ __launch_bounds__(256, 2) void k1_mfma(
    const float* __restrict__ Mh0, const float* __restrict__ Mh1,
    const float* __restrict__ Mh2, const float* __restrict__ Mh3,
    const float* __restrict__ MhB,
    const float* __restrict__ Mv0, const float* __restrict__ Mv1,
    const float* __restrict__ Mv2, const float* __restrict__ Mv3,
    const float* __restrict__ MvB,
    const _Float16* __restrict__ Bfh, const float* __restrict__ bsg,
    float* __restrict__ outs) {
  __shared__ _Float16 Alds[4 * 4 * 2 * 64 * 8];  // [i][m][kb][lane][j] = 32 KB
  __shared__ float MBs[128];                     // MB rows of this l, [row][s]
  __shared__ float bsgs[512];

  const int bd = blockIdx.x >> 10;
  const int l  = blockIdx.x & 1023;
  const float* Ms[4] = {bd ? Mv0 : Mh0, bd ? Mv1 : Mh1, bd ? Mv2 : Mh2, bd ? Mv3 : Mh3};
  const float* MB    = bd ? MvB : MhB;
  const int t = threadIdx.x;

  if (t < 128) MBs[t] = MB[l * 128 + t];
  bsgs[t]       = bsg[t];
  bsgs[256 + t] = bsg[256 + t];

  // stage A: global fp32 -> LDS fp16 in A-frag layout
  #pragma unroll
  for (int i = 0; i < 4; ++i) {
    const float* M = Ms[i] + l * 4096;
    #pragma unroll
    for (int c0 = 0; c0 < 4; ++c0) {
      const int c = t + c0 * 256;            // 0..1023 float4-chunks
      const int row = c >> 4;
      const int v4  = (c & 15) << 2;
      const float4 f = *(const float4*)(M + row * 64 + v4);
      const int m     = row >> 4;
      const int lane2 = (row & 15) | (((v4 >> 3) & 3) << 4);
      const int kb    = v4 >> 5;
      const int jj    = v4 & 7;
      half4v* dst = (half4v*)&Alds[((((i * 4 + m) * 2 + kb) * 64 + lane2) << 3) + jj];
      *dst = (half4v){(_Float16)f.x, (_Float16)f.y, (_Float16)f.z, (_Float16)f.w};
    }
  }
  __syncthreads();

  const int w    = t >> 6;
  const int lane = t & 63;

  float4v E[4][4];   // [m][n], reg r -> row (lane>>4)*4+r, col lane&15
  #pragma unroll
  for (int i = 0; i < 4; ++i) {
    float4v acc[4][4];
    #pragma unroll
    for (int m = 0; m < 4; ++m)
      #pragma unroll
      for (int n = 0; n < 4; ++n) acc[m][n] = (float4v){0.f, 0.f, 0.f, 0.f};
    f16x8 Bf[2][4];
    #pragma unroll
    for (int kb = 0; kb < 2; ++kb)
      #pragma unroll
      for (int n = 0; n < 4; ++n)
        Bf[kb][n] = *(const f16x8*)(Bfh + ((((i * 2 + kb) * 16 + (w * 4 + n)) * 64 + lane) << 3));
    #pragma unroll
    for (int kb = 0; kb < 2; ++kb)
      #pragma unroll
      for (int m = 0; m < 4; ++m) {
        const f16x8 Af = *(const f16x8*)&Alds[((((i * 4 + m) * 2 + kb) * 64 + lane) << 3)];
        #pragma unroll
        for (int n = 0; n < 4; ++n)
          acc[m][n] = __builtin_amdgcn_mfma_f32_16x16x32_f16(Af, Bf[kb][n], acc[m][n], 0, 0, 0);
      }
    if (i == 0) {
      #pragma unroll
      for (int m = 0; m < 4; ++m)
        #pragma unroll
        for (int n = 0; n < 4; ++n) E[m][n] = acc[m][n];
    } else {
      #pragma unroll
      for (int m = 0; m < 4; ++m)
        #pragma unroll
        for (int n = 0; n < 4; ++n) E[m][n] *= acc[m][n];
    }
  }

  // epilogue: * Bdot, reduce over 64 rows, write outs[d][l][hn]
  const int q = lane >> 4, col = lane & 15;
  #pragma unroll
  for (int n = 0; n < 4; ++n) {
    const int hn = w * 64 + n * 16 + col;
    const float b0 = bsgs[hn], b1 = bsgs[256 + hn];
    float ssum = 0.f;
    #pragma unroll
    for (int m = 0; m < 4; ++m)
      #pragma unroll
      for (int r = 0; r < 4; ++r) {
        const int row = m * 16 + q * 4 + r;
        const float bdot = MBs[row * 2] * b0 + MBs[row * 2 + 1] * b1;
        ssum = fmaf(E[m][n][r], bdot, ssum);
      }
    ssum += __shfl_xor(ssum, 16);
    ssum += __shfl_xor(ssum, 32);
    if (lane < 16) outs[(bd * 1024 + l) * 256 + hn] = ssum;
  }
}

// ---------------- K2: build combined 63x63 kernel ----------------
__global__ void k2_kc(const float* __restrict__ outs, const float* __restrict__ C1,
                      const float* __restrict__ C2, float* __restrict__ kc) {
  const int c = blockIdx.x;  // channel 0..31
  const float SC = 0.70710678118654752f;
  for (int idx = threadIdx.x; idx < 63 * 64; idx += 256) {
    const int U = idx >> 6, V = idx & 63;
    float acc = 0.f;
    if (V < 63) {
      const int u = U - 31, v = V - 31;
      #pragma unroll
      for (int d = 0; d < 4; ++d) {
        const int dy = (d == 1 || d == 3) ? u : -u;
        const int dx = (d == 2 || d == 3) ? v : -v;
        if (dy >= 0 && dy < 32 && dx >= 0 && dx < 32) {
          const int l = dy * 32 + dx;
          const int h = d * 32 + c;
          const float e = (dy == 0 && dx == 0) ? 1.f : ((dy == 0 || dx == 0) ? 2.f : 1.f);
          const float s0 = outs[l * 256 + h * 2 + 0] * C1[h * 2 + 0]
                         + outs[l * 256 + h * 2 + 1] * C1[h * 2 + 1];
          const float s1 = outs[262144 + l * 256 + h * 2 + 0] * C2[h * 2 + 0]
                         + outs[262144 + l * 256 + h * 2 + 1] * C2[h * 2 + 1];
          acc += e * SC * (s0 + s1);
        }
      }
    }
    kc[(c * 63 + U) * 64 + V] = acc;
  }
}

// ---------------- K3: transpose x (b,p,q,c) -> (b,c,p,q) ----------------
__global__ void k3_xt(const float* __restrict__ x, float* __restrict__ xt) {
  __shared__ float ls[8 * 64 * 33];
  const int b = blockIdx.x >> 3, pt = blockIdx.x & 7;
  const int t = threadIdx.x;
  const float* src = x + (b * 8 + pt) * 16384;
  #pragma unroll 8
  for (int k = 0; k < 64; ++k) {
    const int e = t + k * 256;
    const int p = e >> 11, q = (e >> 5) & 63, cl = e & 31;
    ls[(p * 64 + q) * 33 + cl] = src[e];
  }
  __syncthreads();
  #pragma unroll 8
  for (int k = 0; k < 64; ++k) {
    const int o = t + k * 256;
    const int cl = o >> 9, p = (o >> 6) & 7, q = o & 63;
    xt[(b * 32 + cl) * 4096 + (pt * 8 + p) * 64 + q] = ls[(p * 64 + q) * 33 + cl];
  }
}

// ---------------- K4: direct conv with combined kernel ----------------
__global__ __launch_bounds__(256, 2) void k4_conv(const float* __restrict__ xt,
                                                  const float* __restrict__ kc,
                                                  float* __restrict__ y) {
  __shared__ float xp[94 * 128];  // rows p0-31..p0+62, cols -31..95 (zero padded)
  const int blk = blockIdx.x;
  const int bc = blk >> 1;           // b*32+c
  const int p0 = (blk & 1) * 32;
  const int t = threadIdx.x;
  const float* xim = xt + bc * 4096;

  for (int idx = t; idx < 94 * 128; idx += 256) {
    const int r = idx >> 7, ccol = idx & 127;
    const int gp = p0 + r - 31, gq = ccol - 31;
    float vv = 0.f;
    if (gp >= 0 && gp < 64 && gq >= 0 && gq < 64) vv = xim[gp * 64 + gq];
    xp[idx] = vv;
  }
  __syncthreads();

  const int c  = bc & 31;
  const int pl = t >> 3;             // output row (local)
  const int ql = (t & 7) * 8;        // output col base (1x8 tile)
  const float* kcc = kc + c * 63 * 64;

  const int wv  = __builtin_amdgcn_readfirstlane(t >> 6);
  const int plw = wv * 8;            // wave's min pl
  const int Ustart = max(0, 24 - p0 - plw);
  const int Uend   = min(62, 94 - p0 - plw);

  float acc[8];
  #pragma unroll
  for (int q = 0; q < 8; ++q) acc[q] = 0.f;

  for (int U = Ustart; U <= Uend; ++U) {
    const float* xr = xp + (pl + U) * 128 + ql;
    const float* kr = kcc + U * 64;   // uniform -> scalar loads
    #pragma unroll
    for (int Vc = 0; Vc < 64; Vc += 16) {
      float xw[24];
      #pragma unroll
      for (int m = 0; m < 6; ++m) {
        const float4 f4 = *(const float4*)(xr + Vc + m * 4);
        xw[m * 4 + 0] = f4.x; xw[m * 4 + 1] = f4.y;
        xw[m * 4 + 2] = f4.z; xw[m * 4 + 3] = f4.w;
      }
      #pragma unroll
      for (int vv = 0; vv < 16; ++vv) {
        const float kv = kr[Vc + vv];
        #pragma unroll
        for (int q = 0; q < 8; ++q)
          acc[q] = fmaf(kv, xw[vv + q], acc[q]);
      }
    }
  }
  float* yrow = y + bc * 4096 + (p0 + pl) * 64 + ql;
  float4 s0 = {acc[0], acc[1], acc[2], acc[3]};
  float4 s1 = {acc[4], acc[5], acc[6], acc[7]};
  *(float4*)(yrow)     = s0;
  *(float4*)(yrow + 4) = s1;
}

// ---------------- K5: channel mix y @ W^T + b ----------------
__global__ void k5_out(const float* __restrict__ yc, const float* __restrict__ W,
                       const float* __restrict__ bias, float* __restrict__ out) {
  __shared__ float ysh[64 * 33];  // [q][c] padded
  const int b = blockIdx.x >> 6, p = blockIdx.x & 63;
  const int t = threadIdx.x;
  const float* ybp = yc + b * 131072 + p * 64;
  #pragma unroll
  for (int k = 0; k < 8; ++k) {
    const int f = t + k * 256;
    const int cch = f >> 6, q = f & 63;
    ysh[q * 33 + cch] = ybp[cch * 4096 + q];
  }
  const int e = t & 31;
  float wr[32];
  #pragma unroll
  for (int c4 = 0; c4 < 8; ++c4) {
    const float4 f4 = *(const float4*)(W + e * 32 + c4 * 4);
    wr[c4 * 4 + 0] = f4.x; wr[c4 * 4 + 1] = f4.y;
    wr[c4 * 4 + 2] = f4.z; wr[c4 * 4 + 3] = f4.w;
  }
  const float bb = bias[e];
  __syncthreads();
  const int q0 = t >> 5;  // 0..7
  #pragma unroll
  for (int k = 0; k < 8; ++k) {
    const int q = q0 + k * 8;
    float a = bb;
    #pragma unroll
    for (int cc = 0; cc < 32; ++cc) a = fmaf(ysh[q * 33 + cc], wr[cc], a);
    out[((b * 64 + p) * 64 + q) * 32 + e] = a;
  }
}

extern "C" void kernel_launch(void* const* d_in, const int* in_sizes, int n_in,
                              void* d_out, int out_size, void* d_ws, size_t ws_size,
                              hipStream_t stream) {
  const float* x   = (const float*)d_in[0];
  const float* Mh[5] = {(const float*)d_in[1], (const float*)d_in[2], (const float*)d_in[3],
                        (const float*)d_in[4], (const float*)d_in[5]};
  const float* Mv[5] = {(const float*)d_in[6], (const float*)d_in[7], (const float*)d_in[8],
                        (const float*)d_in[9], (const float*)d_in[10]};
  const float* A1 = (const float*)d_in[11];
  const float* A2 = (const float*)d_in[12];
  const float* A3 = (const float*)d_in[13];
  const float* A4 = (const float*)d_in[14];
  const float* B1 = (const float*)d_in[15];
  const float* B2 = (const float*)d_in[16];
  const float* C1 = (const float*)d_in[17];
  const float* C2 = (const float*)d_in[18];
  const float* W  = (const float*)d_in[19];
  const float* bb = (const float*)d_in[20];
  float* ws  = (float*)d_ws;
  _Float16* Bfh = (_Float16*)(ws + WS_BFH);
  float* bsg  = ws + WS_BSG;
  float* outs = ws + WS_OUTS;
  float* kc   = ws + WS_KC;
  float* xt   = ws + WS_XT;
  float* yc   = ws + WS_YC;

  k0_prep<<<8, 256, 0, stream>>>(A1, A2, A3, A4, B1, B2, Bfh, bsg);
  k3_xt<<<64, 256, 0, stream>>>(x, xt);
  k1_mfma<<<2048, 256, 0, stream>>>(Mh[0], Mh[1], Mh[2], Mh[3], Mh[4],
                                    Mv[0], Mv[1], Mv[2], Mv[3], Mv[4],
                                    Bfh, bsg, outs);
  k2_kc<<<32, 256, 0, stream>>>(outs, C1, C2, kc);
  k4_conv<<<512, 256, 0, stream>>>(xt, kc, yc);
  k5_out<<<512, 256, 0, stream>>>(yc, W, bb, (float*)d_out);
}

// Round 4
// 288.055 us; speedup vs baseline: 2.9633x; 1.6986x over previous
//
#include <hip/hip_runtime.h>
#include <hip/hip_fp16.h>

typedef _Float16 f16x8 __attribute__((ext_vector_type(8)));
typedef _Float16 half4v __attribute__((ext_vector_type(4)));
typedef float float4v __attribute__((ext_vector_type(4)));
typedef __attribute__((ext_vector_type(8))) short short8;
typedef __attribute__((ext_vector_type(16))) float f32x16;

// workspace layout (float offsets)
#define WS_BFH   0          // 65536 halfs: apw in MFMA B-frag fp16 layout
#define WS_BSG   65536      // 2*256 sigmoid(B_s)[hn]
#define WS_OUTS  66048      // 2*1024*256 outs[d][l][hn]
#define WS_KC    590336     // 32*63*64 Kcomb[c][U][V] (V=63 zero pad)
#define WS_XPAD  719360     // 256*126*64 halfs: x bf16, 31-row zero pad top/bot
#define WS_YC    1767936    // 8*32*64*64 conv result [b][c][p][q] fp32
#define WS_TF    2816512    // 2016*8*512 halfs: Toeplitz T in B-frag bf16 layout

__device__ inline unsigned short f2bf(float f) {
  unsigned int u = __float_as_uint(f);
  u += 0x7fffu + ((u >> 16) & 1u);
  return (unsigned short)(u >> 16);
}

// ---------------- K0: sigmoid powers -> fp16 B-fragment layout ----------------
__global__ void k0_prep(const float* __restrict__ A1, const float* __restrict__ A2,
                        const float* __restrict__ A3, const float* __restrict__ A4,
                        const float* __restrict__ B1, const float* __restrict__ B2,
                        _Float16* __restrict__ Bfh, float* __restrict__ bsg) {
  const int blk = blockIdx.x;        // 0..7 = i*2 + kb
  const int i = blk >> 1, kb = blk & 1;
  const int hn = threadIdx.x;        // 0..255
  const float* As[4] = {A1, A2, A3, A4};
  const float a = As[i][hn];
  const float s = 1.0f / (1.0f + expf(-a));
  float p = 1.0f;
  for (int v = 0; v < kb * 32; ++v) p *= s;
  const int ntile = hn >> 4;
  #pragma unroll
  for (int g = 0; g < 4; ++g) {
    _Float16 h[8];
    #pragma unroll
    for (int j = 0; j < 8; ++j) { h[j] = (_Float16)p; p *= s; }
    const int lane = (hn & 15) | (g << 4);
    _Float16* dst = Bfh + ((((i * 2 + kb) * 16 + ntile) * 64 + lane) << 3);
    *(f16x8*)dst = *(f16x8*)h;
  }
  if (blk == 0) {
    bsg[hn]       = 1.0f / (1.0f + expf(-B1[hn]));
    bsg[256 + hn] = 1.0f / (1.0f + expf(-B2[hn]));
  }
}

// ---------------- K1: SSM kernel contraction via MFMA ----------------
__global__ __launch_bounds__(256, 2) void k1_mfma(
    const float* __restrict__ Mh0, const float* __restrict__ Mh1,
    const float* __restrict__ Mh2, const float* __restrict__ Mh3,
    const float* __restrict__ MhB,
    const float* __restrict__ Mv0, const float* __restrict__ Mv1,
    const float* __restrict__ Mv2, const float* __restrict__ Mv3,
    const float* __restrict__ MvB,
    const _Float16* __restrict__ Bfh, const float* __restrict__ bsg,
    float* __restrict__ outs) {
  __shared__ _Float16 Alds[4 * 4 * 2 * 64 * 8];  // [i][m][kb][lane][j] = 32 KB
  __shared__ float MBs[128];
  __shared__ float bsgs[512];

  const int bd = blockIdx.x >> 10;
  const int l  = blockIdx.x & 1023;
  const float* Ms[4] = {bd ? Mv0 : Mh0, bd ? Mv1 : Mh1, bd ? Mv2 : Mh2, bd ? Mv3 : Mh3};
  const float* MB    = bd ? MvB : MhB;
  const int t = threadIdx.x;

  if (t < 128) MBs[t] = MB[l * 128 + t];
  bsgs[t]       = bsg[t];
  bsgs[256 + t] = bsg[256 + t];

  #pragma unroll
  for (int i = 0; i < 4; ++i) {
    const float* M = Ms[i] + l * 4096;
    #pragma unroll
    for (int c0 = 0; c0 < 4; ++c0) {
      const int c = t + c0 * 256;
      const int row = c >> 4;
      const int v4  = (c & 15) << 2;
      const float4 f = *(const float4*)(M + row * 64 + v4);
      const int m     = row >> 4;
      const int lane2 = (row & 15) | (((v4 >> 3) & 3) << 4);
      const int kb    = v4 >> 5;
      const int jj    = v4 & 7;
      half4v* dst = (half4v*)&Alds[((((i * 4 + m) * 2 + kb) * 64 + lane2) << 3) + jj];
      *dst = (half4v){(_Float16)f.x, (_Float16)f.y, (_Float16)f.z, (_Float16)f.w};
    }
  }
  __syncthreads();

  const int w    = t >> 6;
  const int lane = t & 63;

  float4v E[4][4];
  #pragma unroll
  for (int i = 0; i < 4; ++i) {
    float4v acc[4][4];
    #pragma unroll
    for (int m = 0; m < 4; ++m)
      #pragma unroll
      for (int n = 0; n < 4; ++n) acc[m][n] = (float4v){0.f, 0.f, 0.f, 0.f};
    f16x8 Bf[2][4];
    #pragma unroll
    for (int kb = 0; kb < 2; ++kb)
      #pragma unroll
      for (int n = 0; n < 4; ++n)
        Bf[kb][n] = *(const f16x8*)(Bfh + ((((i * 2 + kb) * 16 + (w * 4 + n)) * 64 + lane) << 3));
    #pragma unroll
    for (int kb = 0; kb < 2; ++kb)
      #pragma unroll
      for (int m = 0; m < 4; ++m) {
        const f16x8 Af = *(const f16x8*)&Alds[((((i * 4 + m) * 2 + kb) * 64 + lane) << 3)];
        #pragma unroll
        for (int n = 0; n < 4; ++n)
          acc[m][n] = __builtin_amdgcn_mfma_f32_16x16x32_f16(Af, Bf[kb][n], acc[m][n], 0, 0, 0);
      }
    if (i == 0) {
      #pragma unroll
      for (int m = 0; m < 4; ++m)
        #pragma unroll
        for (int n = 0; n < 4; ++n) E[m][n] = acc[m][n];
    } else {
      #pragma unroll
      for (int m = 0; m < 4; ++m)
        #pragma unroll
        for (int n = 0; n < 4; ++n) E[m][n] *= acc[m][n];
    }
  }

  const int q = lane >> 4, col = lane & 15;
  #pragma unroll
  for (int n = 0; n < 4; ++n) {
    const int hn = w * 64 + n * 16 + col;
    const float b0 = bsgs[hn], b1 = bsgs[256 + hn];
    float ssum = 0.f;
    #pragma unroll
    for (int m = 0; m < 4; ++m)
      #pragma unroll
      for (int r = 0; r < 4; ++r) {
        const int row = m * 16 + q * 4 + r;
        const float bdot = MBs[row * 2] * b0 + MBs[row * 2 + 1] * b1;
        ssum = fmaf(E[m][n][r], bdot, ssum);
      }
    ssum += __shfl_xor(ssum, 16);
    ssum += __shfl_xor(ssum, 32);
    if (lane < 16) outs[(bd * 1024 + l) * 256 + hn] = ssum;
  }
}

// ---------------- K2: build combined 63x63 kernel ----------------
__global__ void k2_kc(const float* __restrict__ outs, const float* __restrict__ C1,
                      const float* __restrict__ C2, float* __restrict__ kc) {
  const int c = blockIdx.x;
  const float SC = 0.70710678118654752f;
  for (int idx = threadIdx.x; idx < 63 * 64; idx += 256) {
    const int U = idx >> 6, V = idx & 63;
    float acc = 0.f;
    if (V < 63) {
      const int u = U - 31, v = V - 31;
      #pragma unroll
      for (int d = 0; d < 4; ++d) {
        const int dy = (d == 1 || d == 3) ? u : -u;
        const int dx = (d == 2 || d == 3) ? v : -v;
        if (dy >= 0 && dy < 32 && dx >= 0 && dx < 32) {
          const int l = dy * 32 + dx;
          const int h = d * 32 + c;
          const float e = (dy == 0 && dx == 0) ? 1.f : ((dy == 0 || dx == 0) ? 2.f : 1.f);
          const float s0 = outs[l * 256 + h * 2 + 0] * C1[h * 2 + 0]
                         + outs[l * 256 + h * 2 + 1] * C1[h * 2 + 1];
          const float s1 = outs[262144 + l * 256 + h * 2 + 0] * C2[h * 2 + 0]
                         + outs[262144 + l * 256 + h * 2 + 1] * C2[h * 2 + 1];
          acc += e * SC * (s0 + s1);
        }
      }
    }
    kc[(c * 63 + U) * 64 + V] = acc;
  }
}

// ---------------- K2b: kc -> Toeplitz T in bf16 B-frag layout ----------------
// For (c,u): B[k][n] = T_u[k][n] = kc[c][u][k-n+31] (0 outside band); k = input
// column (contraction index), n = output column.
// Frag layout: Tf[(cu*8 + kt*2+nt)*512 + lane*8 + j], k = kt*16+(lane>>5)*8+j,
// n = nt*32 + (lane&31).
__global__ void k2b_tfrag(const float* __restrict__ kc, unsigned short* __restrict__ Tf) {
  const int cu = blockIdx.x;          // c*63+u
  const float* kcr = kc + cu * 64;
  const int t = threadIdx.x;
  #pragma unroll
  for (int s = 0; s < 2; ++s) {
    const int slot = t + s * 256;     // 0..511
    const int f = slot >> 6, lane = slot & 63;
    const int kt = f >> 1, nt = f & 1;
    const int kbase = kt * 16 + (lane >> 5) * 8;
    const int n = nt * 32 + (lane & 31);
    unsigned int o[4];
    #pragma unroll
    for (int jp = 0; jp < 4; ++jp) {
      unsigned short h0, h1;
      {
        const int v = (kbase + 2 * jp) - n + 31;
        h0 = (v >= 0 && v < 63) ? f2bf(kcr[v]) : 0;
      }
      {
        const int v = (kbase + 2 * jp + 1) - n + 31;
        h1 = (v >= 0 && v < 63) ? f2bf(kcr[v]) : 0;
      }
      o[jp] = (unsigned int)h0 | ((unsigned int)h1 << 16);
    }
    unsigned int* dst = (unsigned int*)(Tf + (cu * 8 + f) * 512 + lane * 8);
    dst[0] = o[0]; dst[1] = o[1]; dst[2] = o[2]; dst[3] = o[3];
  }
}

// ---------------- K3: transpose x (b,p,q,c) -> bf16 padded [bc][p+31][q] ----------------
__global__ void k3_xt(const float* __restrict__ x, unsigned short* __restrict__ Xpad) {
  __shared__ float ls[8 * 64 * 33];
  const int b = blockIdx.x >> 3, pt = blockIdx.x & 7;
  const int t = threadIdx.x;
  const float* src = x + (b * 8 + pt) * 16384;
  #pragma unroll 8
  for (int k = 0; k < 64; ++k) {
    const int e = t + k * 256;
    const int p = e >> 11, q = (e >> 5) & 63, cl = e & 31;
    ls[(p * 64 + q) * 33 + cl] = src[e];
  }
  // zero the pad rows (disjoint from data rows)
  unsigned int* Xp32 = (unsigned int*)Xpad;
  if (pt == 0) {
    for (int idx = t; idx < 31744; idx += 256) {     // 32c * 992 uints (rows 0..30)
      const int c = idx / 992, r = idx - c * 992;
      Xp32[(b * 32 + c) * 4032 + r] = 0u;
    }
  }
  if (pt == 7) {
    for (int idx = t; idx < 31744; idx += 256) {     // rows 95..125
      const int c = idx / 992, r = idx - c * 992;
      Xp32[(b * 32 + c) * 4032 + 3040 + r] = 0u;
    }
  }
  __syncthreads();
  #pragma unroll 8
  for (int k = 0; k < 32; ++k) {
    const int o = t + k * 256;                        // 8192 q-pairs
    const int cl = o >> 8, p = (o >> 5) & 7, q2 = o & 31;
    const float f0 = ls[(p * 64 + 2 * q2 + 0) * 33 + cl];
    const float f1 = ls[(p * 64 + 2 * q2 + 1) * 33 + cl];
    const unsigned int pk = (unsigned int)f2bf(f0) | ((unsigned int)f2bf(f1) << 16);
    Xp32[(b * 32 + cl) * 4032 + (pt * 8 + p + 31) * 32 + q2] = pk;
  }
}

// ---------------- K4b: conv as sum of 63 Toeplitz GEMMs (MFMA bf16) ----------------
// Block = (b,c). Y(64x64) = sum_u Xpad[rows p+u] @ T_u. Waves split u mod 4.
__global__ __launch_bounds__(256, 1) void k4b_conv(const unsigned short* __restrict__ Xpad,
                                                   const unsigned short* __restrict__ Tf,
                                                   float* __restrict__ yc) {
  __shared__ float red[4 * 4096];
  const int bc = blockIdx.x;
  const int c  = bc & 31;
  const int t = threadIdx.x, w = t >> 6, lane = t & 63;
  const unsigned short* Xp = Xpad + bc * 8064;
  const unsigned short* Tc = Tf + c * 63 * 4096;
  const int r = lane & 31, kh = lane >> 5;

  f32x16 acc[2][2];
  #pragma unroll
  for (int m = 0; m < 2; ++m)
    #pragma unroll
    for (int n = 0; n < 2; ++n)
      #pragma unroll
      for (int e = 0; e < 16; ++e) acc[m][n][e] = 0.f;

  short8 Ac[2][4], Bc[4][2];
  int u = w;
  #pragma unroll
  for (int m = 0; m < 2; ++m)
    #pragma unroll
    for (int kt = 0; kt < 4; ++kt)
      Ac[m][kt] = *(const short8*)(Xp + (m * 32 + r + u) * 64 + kt * 16 + kh * 8);
  #pragma unroll
  for (int kt = 0; kt < 4; ++kt)
    #pragma unroll
    for (int nt = 0; nt < 2; ++nt)
      Bc[kt][nt] = *(const short8*)(Tc + (u * 8 + kt * 2 + nt) * 512 + lane * 8);

  for (int i = 0; i < 16; ++i) {
    const int un = u + 4;
    const bool has_next = (un < 63);
    short8 An[2][4], Bn[4][2];
    if (has_next) {
      #pragma unroll
      for (int m = 0; m < 2; ++m)
        #pragma unroll
        for (int kt = 0; kt < 4; ++kt)
          An[m][kt] = *(const short8*)(Xp + (m * 32 + r + un) * 64 + kt * 16 + kh * 8);
      #pragma unroll
      for (int kt = 0; kt < 4; ++kt)
        #pragma unroll
        for (int nt = 0; nt < 2; ++nt)
          Bn[kt][nt] = *(const short8*)(Tc + (un * 8 + kt * 2 + nt) * 512 + lane * 8);
    }
    #pragma unroll
    for (int kt = 0; kt < 4; ++kt)
      #pragma unroll
      for (int m = 0; m < 2; ++m)
        #pragma unroll
        for (int nt = 0; nt < 2; ++nt)
          acc[m][nt] = __builtin_amdgcn_mfma_f32_32x32x16_bf16(Ac[m][kt], Bc[kt][nt],
                                                               acc[m][nt], 0, 0, 0);
    if (!has_next) break;
    #pragma unroll
    for (int m = 0; m < 2; ++m)
      #pragma unroll
      for (int kt = 0; kt < 4; ++kt) Ac[m][kt] = An[m][kt];
    #pragma unroll
    for (int kt = 0; kt < 4; ++kt)
      #pragma unroll
      for (int nt = 0; nt < 2; ++nt) Bc[kt][nt] = Bn[kt][nt];
    u = un;
  }

  // write wave partials (C layout: col=lane&31, row=(reg&3)+8*(reg>>2)+4*(lane>>5))
  float* my = red + w * 4096;
  #pragma unroll
  for (int m = 0; m < 2; ++m)
    #pragma unroll
    for (int nt = 0; nt < 2; ++nt)
      #pragma unroll
      for (int e = 0; e < 16; ++e) {
        const int row = (e & 3) + 8 * (e >> 2) + 4 * kh;
        my[(m * 32 + row) * 64 + nt * 32 + r] = acc[m][nt][e];
      }
  __syncthreads();
  float* out = yc + bc * 4096;
  #pragma unroll
  for (int k = 0; k < 16; ++k) {
    const int idx = t + k * 256;
    out[idx] = red[idx] + red[4096 + idx] + red[8192 + idx] + red[12288 + idx];
  }
}

// ---------------- K5: channel mix y @ W^T + b ----------------
__global__ void k5_out(const float* __restrict__ yc, const float* __restrict__ W,
                       const float* __restrict__ bias, float* __restrict__ out) {
  __shared__ float ysh[64 * 33];
  const int b = blockIdx.x >> 6, p = blockIdx.x & 63;
  const int t = threadIdx.x;
  const float* ybp = yc + b * 131072 + p * 64;
  #pragma unroll
  for (int k = 0; k < 8; ++k) {
    const int f = t + k * 256;
    const int cch = f >> 6, q = f & 63;
    ysh[q * 33 + cch] = ybp[cch * 4096 + q];
  }
  const int e = t & 31;
  float wr[32];
  #pragma unroll
  for (int c4 = 0; c4 < 8; ++c4) {
    const float4 f4 = *(const float4*)(W + e * 32 + c4 * 4);
    wr[c4 * 4 + 0] = f4.x; wr[c4 * 4 + 1] = f4.y;
    wr[c4 * 4 + 2] = f4.z; wr[c4 * 4 + 3] = f4.w;
  }
  const float bb = bias[e];
  __syncthreads();
  const int q0 = t >> 5;
  #pragma unroll
  for (int k = 0; k < 8; ++k) {
    const int q = q0 + k * 8;
    float a = bb;
    #pragma unroll
    for (int cc = 0; cc < 32; ++cc) a = fmaf(ysh[q * 33 + cc], wr[cc], a);
    out[((b * 64 + p) * 64 + q) * 32 + e] = a;
  }
}

extern "C" void kernel_launch(void* const* d_in, const int* in_sizes, int n_in,
                              void* d_out, int out_size, void* d_ws, size_t ws_size,
                              hipStream_t stream) {
  const float* x   = (const float*)d_in[0];
  const float* Mh[5] = {(const float*)d_in[1], (const float*)d_in[2], (const float*)d_in[3],
                        (const float*)d_in[4], (const float*)d_in[5]};
  const float* Mv[5] = {(const float*)d_in[6], (const float*)d_in[7], (const float*)d_in[8],
                        (const float*)d_in[9], (const float*)d_in[10]};
  const float* A1 = (const float*)d_in[11];
  const float* A2 = (const float*)d_in[12];
  const float* A3 = (const float*)d_in[13];
  const float* A4 = (const float*)d_in[14];
  const float* B1 = (const float*)d_in[15];
  const float* B2 = (const float*)d_in[16];
  const float* C1 = (const float*)d_in[17];
  const float* C2 = (const float*)d_in[18];
  const float* W  = (const float*)d_in[19];
  const float* bb = (const float*)d_in[20];
  float* ws  = (float*)d_ws;
  _Float16* Bfh = (_Float16*)(ws + WS_BFH);
  float* bsg  = ws + WS_BSG;
  float* outs = ws + WS_OUTS;
  float* kc   = ws + WS_KC;
  unsigned short* Xpad = (unsigned short*)(ws + WS_XPAD);
  float* yc   = ws + WS_YC;
  unsigned short* Tf = (unsigned short*)(ws + WS_TF);

  k0_prep<<<8, 256, 0, stream>>>(A1, A2, A3, A4, B1, B2, Bfh, bsg);
  k3_xt<<<64, 256, 0, stream>>>(x, Xpad);
  k1_mfma<<<2048, 256, 0, stream>>>(Mh[0], Mh[1], Mh[2], Mh[3], Mh[4],
                                    Mv[0], Mv[1], Mv[2], Mv[3], Mv[4],
                                    Bfh, bsg, outs);
  k2_kc<<<32, 256, 0, stream>>>(outs, C1, C2, kc);
  k2b_tfrag<<<2016, 256, 0, stream>>>(kc, Tf);
  k4b_conv<<<256, 256, 0, stream>>>(Xpad, Tf, yc);
  k5_out<<<512, 256, 0, stream>>>(yc, W, bb, (float*)d_out);
}

// Round 5
// 272.788 us; speedup vs baseline: 3.1292x; 1.0560x over previous
//
#include <hip/hip_runtime.h>
#include <hip/hip_fp16.h>

typedef _Float16 f16x8 __attribute__((ext_vector_type(8)));
typedef _Float16 half4v __attribute__((ext_vector_type(4)));
typedef float float4v __attribute__((ext_vector_type(4)));
typedef __attribute__((ext_vector_type(8))) short short8;
typedef __attribute__((ext_vector_type(16))) float f32x16;

// workspace layout (float offsets)
#define WS_BFH   0          // 65536 halfs: apw in MFMA B-frag fp16 layout
#define WS_BSG   65536      // 2*256 sigmoid(B_s)[hn]
#define WS_OUTS  66048      // 2*1024*256 outs[d][l][hn]
#define WS_KC    590336     // 32*63*64 Kcomb[c][U][V] (V=63 zero pad)
#define WS_XPAD  719360     // 256*126*64 halfs: x bf16, 31-row zero pad top/bot
#define WS_YC    1767936    // 8*32*64*64 conv result [b][c][p][q] fp32
#define WS_TF    2816512    // 2016*8*512 halfs: Toeplitz T in B-frag bf16 layout

__device__ inline unsigned short f2bf(float f) {
  unsigned int u = __float_as_uint(f);
  u += 0x7fffu + ((u >> 16) & 1u);
  return (unsigned short)(u >> 16);
}

// ---------------- K0: sigmoid powers -> fp16 B-fragment layout ----------------
__global__ void k0_prep(const float* __restrict__ A1, const float* __restrict__ A2,
                        const float* __restrict__ A3, const float* __restrict__ A4,
                        const float* __restrict__ B1, const float* __restrict__ B2,
                        _Float16* __restrict__ Bfh, float* __restrict__ bsg) {
  const int blk = blockIdx.x;        // 0..7 = i*2 + kb
  const int i = blk >> 1, kb = blk & 1;
  const int hn = threadIdx.x;        // 0..255
  const float* As[4] = {A1, A2, A3, A4};
  const float a = As[i][hn];
  const float s = 1.0f / (1.0f + expf(-a));
  float p = 1.0f;
  for (int v = 0; v < kb * 32; ++v) p *= s;
  const int ntile = hn >> 4;
  #pragma unroll
  for (int g = 0; g < 4; ++g) {
    _Float16 h[8];
    #pragma unroll
    for (int j = 0; j < 8; ++j) { h[j] = (_Float16)p; p *= s; }
    const int lane = (hn & 15) | (g << 4);
    _Float16* dst = Bfh + ((((i * 2 + kb) * 16 + ntile) * 64 + lane) << 3);
    *(f16x8*)dst = *(f16x8*)h;
  }
  if (blk == 0) {
    bsg[hn]       = 1.0f / (1.0f + expf(-B1[hn]));
    bsg[256 + hn] = 1.0f / (1.0f + expf(-B2[hn]));
  }
}

// ---------------- K1: SSM kernel contraction via MFMA ----------------
// Two n-passes of 2 n-tiles each -> acc state 64 regs -> 4 blocks/CU.
__global__ __launch_bounds__(256, 4) void k1_mfma(
    const float* __restrict__ Mh0, const float* __restrict__ Mh1,
    const float* __restrict__ Mh2, const float* __restrict__ Mh3,
    const float* __restrict__ MhB,
    const float* __restrict__ Mv0, const float* __restrict__ Mv1,
    const float* __restrict__ Mv2, const float* __restrict__ Mv3,
    const float* __restrict__ MvB,
    const _Float16* __restrict__ Bfh, const float* __restrict__ bsg,
    float* __restrict__ outs) {
  __shared__ _Float16 Alds[4 * 4 * 2 * 64 * 8];  // [i][m][kb][lane][j] = 32 KB
  __shared__ float MBs[128];
  __shared__ float bsgs[512];

  const int bd = blockIdx.x >> 10;
  const int l  = blockIdx.x & 1023;
  const float* Ms[4] = {bd ? Mv0 : Mh0, bd ? Mv1 : Mh1, bd ? Mv2 : Mh2, bd ? Mv3 : Mh3};
  const float* MB    = bd ? MvB : MhB;
  const int t = threadIdx.x;

  if (t < 128) MBs[t] = MB[l * 128 + t];
  bsgs[t]       = bsg[t];
  bsgs[256 + t] = bsg[256 + t];

  #pragma unroll
  for (int i = 0; i < 4; ++i) {
    const float* M = Ms[i] + l * 4096;
    #pragma unroll
    for (int c0 = 0; c0 < 4; ++c0) {
      const int c = t + c0 * 256;
      const int row = c >> 4;
      const int v4  = (c & 15) << 2;
      const float4 f = *(const float4*)(M + row * 64 + v4);
      const int m     = row >> 4;
      const int lane2 = (row & 15) | (((v4 >> 3) & 3) << 4);
      const int kb    = v4 >> 5;
      const int jj    = v4 & 7;
      half4v* dst = (half4v*)&Alds[((((i * 4 + m) * 2 + kb) * 64 + lane2) << 3) + jj];
      *dst = (half4v){(_Float16)f.x, (_Float16)f.y, (_Float16)f.z, (_Float16)f.w};
    }
  }
  __syncthreads();

  const int w    = t >> 6;
  const int lane = t & 63;
  const int q = lane >> 4, col = lane & 15;

  #pragma unroll
  for (int half = 0; half < 2; ++half) {
    float4v E[4][2];
    #pragma unroll
    for (int i = 0; i < 4; ++i) {
      float4v acc[4][2];
      #pragma unroll
      for (int m = 0; m < 4; ++m)
        #pragma unroll
        for (int n = 0; n < 2; ++n) acc[m][n] = (float4v){0.f, 0.f, 0.f, 0.f};
      f16x8 Bf[2][2];
      #pragma unroll
      for (int kb = 0; kb < 2; ++kb)
        #pragma unroll
        for (int n = 0; n < 2; ++n)
          Bf[kb][n] = *(const f16x8*)(Bfh +
              ((((i * 2 + kb) * 16 + (w * 4 + half * 2 + n)) * 64 + lane) << 3));
      #pragma unroll
      for (int kb = 0; kb < 2; ++kb)
        #pragma unroll
        for (int m = 0; m < 4; ++m) {
          const f16x8 Af = *(const f16x8*)&Alds[((((i * 4 + m) * 2 + kb) * 64 + lane) << 3)];
          #pragma unroll
          for (int n = 0; n < 2; ++n)
            acc[m][n] = __builtin_amdgcn_mfma_f32_16x16x32_f16(Af, Bf[kb][n], acc[m][n], 0, 0, 0);
        }
      if (i == 0) {
        #pragma unroll
        for (int m = 0; m < 4; ++m)
          #pragma unroll
          for (int n = 0; n < 2; ++n) E[m][n] = acc[m][n];
      } else {
        #pragma unroll
        for (int m = 0; m < 4; ++m)
          #pragma unroll
          for (int n = 0; n < 2; ++n) E[m][n] *= acc[m][n];
      }
    }

    #pragma unroll
    for (int n = 0; n < 2; ++n) {
      const int hn = w * 64 + (half * 2 + n) * 16 + col;
      const float b0 = bsgs[hn], b1 = bsgs[256 + hn];
      float ssum = 0.f;
      #pragma unroll
      for (int m = 0; m < 4; ++m)
        #pragma unroll
        for (int r = 0; r < 4; ++r) {
          const int row = m * 16 + q * 4 + r;
          const float bdot = MBs[row * 2] * b0 + MBs[row * 2 + 1] * b1;
          ssum = fmaf(E[m][n][r], bdot, ssum);
        }
      ssum += __shfl_xor(ssum, 16);
      ssum += __shfl_xor(ssum, 32);
      if (lane < 16) outs[(bd * 1024 + l) * 256 + hn] = ssum;
    }
  }
}

// ---------------- K2: build combined 63x63 kernel ----------------
__global__ void k2_kc(const float* __restrict__ outs, const float* __restrict__ C1,
                      const float* __restrict__ C2, float* __restrict__ kc) {
  const int c = blockIdx.x;
  const float SC = 0.70710678118654752f;
  for (int idx = threadIdx.x; idx < 63 * 64; idx += 256) {
    const int U = idx >> 6, V = idx & 63;
    float acc = 0.f;
    if (V < 63) {
      const int u = U - 31, v = V - 31;
      #pragma unroll
      for (int d = 0; d < 4; ++d) {
        const int dy = (d == 1 || d == 3) ? u : -u;
        const int dx = (d == 2 || d == 3) ? v : -v;
        if (dy >= 0 && dy < 32 && dx >= 0 && dx < 32) {
          const int l = dy * 32 + dx;
          const int h = d * 32 + c;
          const float e = (dy == 0 && dx == 0) ? 1.f : ((dy == 0 || dx == 0) ? 2.f : 1.f);
          const float s0 = outs[l * 256 + h * 2 + 0] * C1[h * 2 + 0]
                         + outs[l * 256 + h * 2 + 1] * C1[h * 2 + 1];
          const float s1 = outs[262144 + l * 256 + h * 2 + 0] * C2[h * 2 + 0]
                         + outs[262144 + l * 256 + h * 2 + 1] * C2[h * 2 + 1];
          acc += e * SC * (s0 + s1);
        }
      }
    }
    kc[(c * 63 + U) * 64 + V] = acc;
  }
}

// ---------------- K2b: kc -> Toeplitz T in bf16 B-frag layout ----------------
// B[k][n] = T_u[k][n] = kc[c][u][k-n+31] (0 outside band); k = input column.
__global__ void k2b_tfrag(const float* __restrict__ kc, unsigned short* __restrict__ Tf) {
  const int cu = blockIdx.x;          // c*63+u
  const float* kcr = kc + cu * 64;
  const int t = threadIdx.x;
  #pragma unroll
  for (int s = 0; s < 2; ++s) {
    const int slot = t + s * 256;     // 0..511
    const int f = slot >> 6, lane = slot & 63;
    const int kt = f >> 1, nt = f & 1;
    const int kbase = kt * 16 + (lane >> 5) * 8;
    const int n = nt * 32 + (lane & 31);
    unsigned int o[4];
    #pragma unroll
    for (int jp = 0; jp < 4; ++jp) {
      unsigned short h0, h1;
      {
        const int v = (kbase + 2 * jp) - n + 31;
        h0 = (v >= 0 && v < 63) ? f2bf(kcr[v]) : 0;
      }
      {
        const int v = (kbase + 2 * jp + 1) - n + 31;
        h1 = (v >= 0 && v < 63) ? f2bf(kcr[v]) : 0;
      }
      o[jp] = (unsigned int)h0 | ((unsigned int)h1 << 16);
    }
    unsigned int* dst = (unsigned int*)(Tf + (cu * 8 + f) * 512 + lane * 8);
    dst[0] = o[0]; dst[1] = o[1]; dst[2] = o[2]; dst[3] = o[3];
  }
}

// ---------------- K3: transpose x (b,p,q,c) -> bf16 padded [bc][p+31][q] ----------------
// 128 blocks: b = blk>>4, pt = blk&15 (4 rows each).
__global__ void k3_xt(const float* __restrict__ x, unsigned short* __restrict__ Xpad) {
  __shared__ float ls[4 * 64 * 33];
  const int b = blockIdx.x >> 4, pt = blockIdx.x & 15;
  const int t = threadIdx.x;
  const float* src = x + (b * 64 + pt * 4) * 2048;
  #pragma unroll 8
  for (int k = 0; k < 32; ++k) {
    const int e = t + k * 256;                        // 0..8191
    const int p = e >> 11, q = (e >> 5) & 63, cl = e & 31;
    ls[(p * 64 + q) * 33 + cl] = src[e];
  }
  // zero the pad rows (disjoint from data rows)
  unsigned int* Xp32 = (unsigned int*)Xpad;
  if (pt == 0) {
    for (int idx = t; idx < 31744; idx += 256) {     // 32c * 992 uints (rows 0..30)
      const int c = idx / 992, r = idx - c * 992;
      Xp32[(b * 32 + c) * 4032 + r] = 0u;
    }
  }
  if (pt == 15) {
    for (int idx = t; idx < 31744; idx += 256) {     // rows 95..125
      const int c = idx / 992, r = idx - c * 992;
      Xp32[(b * 32 + c) * 4032 + 3040 + r] = 0u;
    }
  }
  __syncthreads();
  #pragma unroll 8
  for (int k = 0; k < 16; ++k) {
    const int o = t + k * 256;                        // 0..4095 q-pairs
    const int cl = o >> 7, p = (o >> 5) & 3, q2 = o & 31;
    const float f0 = ls[(p * 64 + 2 * q2 + 0) * 33 + cl];
    const float f1 = ls[(p * 64 + 2 * q2 + 1) * 33 + cl];
    const unsigned int pk = (unsigned int)f2bf(f0) | ((unsigned int)f2bf(f1) << 16);
    Xp32[(b * 32 + cl) * 4032 + (pt * 4 + p + 31) * 32 + q2] = pk;
  }
}

// ---------------- K4b: conv as sum of 63 Toeplitz GEMMs (MFMA bf16) ----------------
__global__ __launch_bounds__(256, 1) void k4b_conv(const unsigned short* __restrict__ Xpad,
                                                   const unsigned short* __restrict__ Tf,
                                                   float* __restrict__ yc) {
  __shared__ float red[4 * 4096];
  const int bc = blockIdx.x;
  const int c  = bc & 31;
  const int t = threadIdx.x, w = t >> 6, lane = t & 63;
  const unsigned short* Xp = Xpad + bc * 8064;
  const unsigned short* Tc = Tf + c * 63 * 4096;
  const int r = lane & 31, kh = lane >> 5;

  f32x16 acc[2][2];
  #pragma unroll
  for (int m = 0; m < 2; ++m)
    #pragma unroll
    for (int n = 0; n < 2; ++n)
      #pragma unroll
      for (int e = 0; e < 16; ++e) acc[m][n][e] = 0.f;

  short8 Ac[2][4], Bc[4][2];
  int u = w;
  #pragma unroll
  for (int m = 0; m < 2; ++m)
    #pragma unroll
    for (int kt = 0; kt < 4; ++kt)
      Ac[m][kt] = *(const short8*)(Xp + (m * 32 + r + u) * 64 + kt * 16 + kh * 8);
  #pragma unroll
  for (int kt = 0; kt < 4; ++kt)
    #pragma unroll
    for (int nt = 0; nt < 2; ++nt)
      Bc[kt][nt] = *(const short8*)(Tc + (u * 8 + kt * 2 + nt) * 512 + lane * 8);

  for (int i = 0; i < 16; ++i) {
    const int un = u + 4;
    const bool has_next = (un < 63);
    short8 An[2][4], Bn[4][2];
    if (has_next) {
      #pragma unroll
      for (int m = 0; m < 2; ++m)
        #pragma unroll
        for (int kt = 0; kt < 4; ++kt)
          An[m][kt] = *(const short8*)(Xp + (m * 32 + r + un) * 64 + kt * 16 + kh * 8);
      #pragma unroll
      for (int kt = 0; kt < 4; ++kt)
        #pragma unroll
        for (int nt = 0; nt < 2; ++nt)
          Bn[kt][nt] = *(const short8*)(Tc + (un * 8 + kt * 2 + nt) * 512 + lane * 8);
    }
    #pragma unroll
    for (int kt = 0; kt < 4; ++kt)
      #pragma unroll
      for (int m = 0; m < 2; ++m)
        #pragma unroll
        for (int nt = 0; nt < 2; ++nt)
          acc[m][nt] = __builtin_amdgcn_mfma_f32_32x32x16_bf16(Ac[m][kt], Bc[kt][nt],
                                                               acc[m][nt], 0, 0, 0);
    if (!has_next) break;
    #pragma unroll
    for (int m = 0; m < 2; ++m)
      #pragma unroll
      for (int kt = 0; kt < 4; ++kt) Ac[m][kt] = An[m][kt];
    #pragma unroll
    for (int kt = 0; kt < 4; ++kt)
      #pragma unroll
      for (int nt = 0; nt < 2; ++nt) Bc[kt][nt] = Bn[kt][nt];
    u = un;
  }

  // write wave partials (C layout: col=lane&31, row=(reg&3)+8*(reg>>2)+4*(lane>>5))
  float* my = red + w * 4096;
  #pragma unroll
  for (int m = 0; m < 2; ++m)
    #pragma unroll
    for (int nt = 0; nt < 2; ++nt)
      #pragma unroll
      for (int e = 0; e < 16; ++e) {
        const int row = (e & 3) + 8 * (e >> 2) + 4 * kh;
        my[(m * 32 + row) * 64 + nt * 32 + r] = acc[m][nt][e];
      }
  __syncthreads();
  float* out = yc + bc * 4096;
  #pragma unroll
  for (int k = 0; k < 16; ++k) {
    const int idx = t + k * 256;
    out[idx] = red[idx] + red[4096 + idx] + red[8192 + idx] + red[12288 + idx];
  }
}

// ---------------- K5: channel mix y @ W^T + b ----------------
__global__ void k5_out(const float* __restrict__ yc, const float* __restrict__ W,
                       const float* __restrict__ bias, float* __restrict__ out) {
  __shared__ float ysh[64 * 33];
  const int b = blockIdx.x >> 6, p = blockIdx.x & 63;
  const int t = threadIdx.x;
  const float* ybp = yc + b * 131072 + p * 64;
  #pragma unroll
  for (int k = 0; k < 8; ++k) {
    const int f = t + k * 256;
    const int cch = f >> 6, q = f & 63;
    ysh[q * 33 + cch] = ybp[cch * 4096 + q];
  }
  const int e = t & 31;
  float wr[32];
  #pragma unroll
  for (int c4 = 0; c4 < 8; ++c4) {
    const float4 f4 = *(const float4*)(W + e * 32 + c4 * 4);
    wr[c4 * 4 + 0] = f4.x; wr[c4 * 4 + 1] = f4.y;
    wr[c4 * 4 + 2] = f4.z; wr[c4 * 4 + 3] = f4.w;
  }
  const float bb = bias[e];
  __syncthreads();
  const int q0 = t >> 5;
  #pragma unroll
  for (int k = 0; k < 8; ++k) {
    const int q = q0 + k * 8;
    float a = bb;
    #pragma unroll
    for (int cc = 0; cc < 32; ++cc) a = fmaf(ysh[q * 33 + cc], wr[cc], a);
    out[((b * 64 + p) * 64 + q) * 32 + e] = a;
  }
}

extern "C" void kernel_launch(void* const* d_in, const int* in_sizes, int n_in,
                              void* d_out, int out_size, void* d_ws, size_t ws_size,
                              hipStream_t stream) {
  const float* x   = (const float*)d_in[0];
  const float* Mh[5] = {(const float*)d_in[1], (const float*)d_in[2], (const float*)d_in[3],
                        (const float*)d_in[4], (const float*)d_in[5]};
  const float* Mv[5] = {(const float*)d_in[6], (const float*)d_in[7], (const float*)d_in[8],
                        (const float*)d_in[9], (const float*)d_in[10]};
  const float* A1 = (const float*)d_in[11];
  const float* A2 = (const float*)d_in[12];
  const float* A3 = (const float*)d_in[13];
  const float* A4 = (const float*)d_in[14];
  const float* B1 = (const float*)d_in[15];
  const float* B2 = (const float*)d_in[16];
  const float* C1 = (const float*)d_in[17];
  const float* C2 = (const float*)d_in[18];
  const float* W  = (const float*)d_in[19];
  const float* bb = (const float*)d_in[20];
  float* ws  = (float*)d_ws;
  _Float16* Bfh = (_Float16*)(ws + WS_BFH);
  float* bsg  = ws + WS_BSG;
  float* outs = ws + WS_OUTS;
  float* kc   = ws + WS_KC;
  unsigned short* Xpad = (unsigned short*)(ws + WS_XPAD);
  float* yc   = ws + WS_YC;
  unsigned short* Tf = (unsigned short*)(ws + WS_TF);

  k0_prep<<<8, 256, 0, stream>>>(A1, A2, A3, A4, B1, B2, Bfh, bsg);
  k3_xt<<<128, 256, 0, stream>>>(x, Xpad);
  k1_mfma<<<2048, 256, 0, stream>>>(Mh[0], Mh[1], Mh[2], Mh[3], Mh[4],
                                    Mv[0], Mv[1], Mv[2], Mv[3], Mv[4],
                                    Bfh, bsg, outs);
  k2_kc<<<32, 256, 0, stream>>>(outs, C1, C2, kc);
  k2b_tfrag<<<2016, 256, 0, stream>>>(kc, Tf);
  k4b_conv<<<256, 256, 0, stream>>>(Xpad, Tf, yc);
  k5_out<<<512, 256, 0, stream>>>(yc, W, bb, (float*)d_out);
}